// Round 1
// baseline (81.446 us; speedup 1.0000x reference)
//
#include <hip/hip_runtime.h>
#include <cstdint>
#include <cstddef>

#define N_MASKS 96
#define HW (512 * 512)
#define WORDS_PER_ROW (HW / 64)            // 4096 u64 words per mask row
#define TOTAL_WORDS (N_MASKS * WORDS_PER_ROW)
#define P_BOXES 8
#define IOU_THR 0.5f
#define SCORE_THR 0.5f
#define SCORE_BONUS 0.05f

// ---------------------------------------------------------------------------
// Kernel 1: binarize mask logits into bit-packed rows.
// Each wave (64 lanes) loads 64 float4 = 256 elements and emits 4 u64 words
// via __ballot. The bit permutation within a 256-element group is the same
// for every row (rows are 1024 groups each), so AND+popcount is unaffected.
// ---------------------------------------------------------------------------
__global__ __launch_bounds__(256) void pack_kernel(
    const float4* __restrict__ logits,
    unsigned long long* __restrict__ bits,
    int n_groups) {
  int gtid = blockIdx.x * blockDim.x + threadIdx.x;
  int group = gtid >> 6;
  int lane = threadIdx.x & 63;
  if (group >= n_groups) return;  // grid sized exactly; whole waves in-bounds
  float4 v = logits[(size_t)group * 64 + lane];
  unsigned long long m0 = __ballot(v.x > 0.0f);
  unsigned long long m1 = __ballot(v.y > 0.0f);
  unsigned long long m2 = __ballot(v.z > 0.0f);
  unsigned long long m3 = __ballot(v.w > 0.0f);
  if (lane == 0) {
    unsigned long long* dst = bits + (size_t)group * 4;
    dst[0] = m0; dst[1] = m1; dst[2] = m2; dst[3] = m3;
  }
}

// ---------------------------------------------------------------------------
// Kernel 2: pairwise intersection counts (and areas on the diagonal).
// One block per (i,j) with i<=j; 256 threads stride over 4096 words.
// ---------------------------------------------------------------------------
__global__ __launch_bounds__(256) void inter_kernel(
    const unsigned long long* __restrict__ bits,
    int* __restrict__ inter) {
  int i = blockIdx.y, j = blockIdx.x;
  if (j < i) return;
  const unsigned long long* a = bits + (size_t)i * WORDS_PER_ROW;
  const unsigned long long* b = bits + (size_t)j * WORDS_PER_ROW;
  int t = threadIdx.x;
  int acc = 0;
#pragma unroll
  for (int w = 0; w < WORDS_PER_ROW / 256; ++w) {
    int idx = t + w * 256;
    acc += __popcll(a[idx] & b[idx]);
  }
  // wave reduce
  for (int off = 32; off >= 1; off >>= 1) acc += __shfl_xor(acc, off);
  __shared__ int red[4];
  int wave = t >> 6;
  if ((t & 63) == 0) red[wave] = acc;
  __syncthreads();
  if (t == 0) {
    int tot = red[0] + red[1] + red[2] + red[3];
    inter[i * N_MASKS + j] = tot;
    inter[j * N_MASKS + i] = tot;
  }
}

// ---------------------------------------------------------------------------
// Kernel 3: NMS + greedy box matching. Single block, 128 threads (2 waves).
// Wave 0: stable-sorted greedy mask NMS. Wave 1: greedy bipartite matching.
// ---------------------------------------------------------------------------
__global__ __launch_bounds__(128) void finalize_kernel(
    const int* __restrict__ inter,
    const float* __restrict__ scores,
    const float* __restrict__ pboxes,
    const float* __restrict__ qboxes,
    float* __restrict__ out) {
  __shared__ float s_scores[N_MASKS];
  __shared__ float s_iou[N_MASKS * N_MASKS];
  __shared__ int s_order[N_MASKS];
  __shared__ float s_comb[P_BOXES * N_MASKS];
  __shared__ float s_pb[P_BOXES * 4];
  __shared__ float s_qb[N_MASKS * 4];
  int t = threadIdx.x;

  if (t < N_MASKS) s_scores[t] = scores[t];
  for (int k = t; k < P_BOXES * 4; k += 128) s_pb[k] = pboxes[k];
  for (int k = t; k < N_MASKS * 4; k += 128) s_qb[k] = qboxes[k];
  __syncthreads();

  // mask IoU matrix (exact: inter/area are small ints, exact in f32)
  for (int e = t; e < N_MASKS * N_MASKS; e += 128) {
    int i = e / N_MASKS, j = e % N_MASKS;
    float in_ = (float)inter[e];
    float un = (float)inter[i * N_MASKS + i] + (float)inter[j * N_MASKS + j] - in_;
    s_iou[e] = (un > 0.0f) ? in_ / un : 0.0f;
  }
  // stable descending rank of scores (tie -> smaller index first)
  if (t < N_MASKS) {
    float sc = s_scores[t];
    int r = 0;
    for (int m = 0; m < N_MASKS; ++m) {
      float sm = s_scores[m];
      if (sm > sc || (sm == sc && m < t)) ++r;
    }
    s_order[r] = t;
  }
  // combined = box_iou(prompt, query) + bonus * score
  for (int f = t; f < P_BOXES * N_MASKS; f += 128) {
    int p = f / N_MASKS, q = f % N_MASKS;
    float ax0 = s_pb[p * 4 + 0], ay0 = s_pb[p * 4 + 1];
    float ax1 = s_pb[p * 4 + 2], ay1 = s_pb[p * 4 + 3];
    float bx0 = s_qb[q * 4 + 0], by0 = s_qb[q * 4 + 1];
    float bx1 = s_qb[q * 4 + 2], by1 = s_qb[q * 4 + 3];
    float ltx = fmaxf(ax0, bx0), lty = fmaxf(ay0, by0);
    float rbx = fminf(ax1, bx1), rby = fminf(ay1, by1);
    float w = fmaxf(rbx - ltx, 0.0f), h = fmaxf(rby - lty, 0.0f);
    float in_ = w * h;
    float aa = fmaxf(ax1 - ax0, 0.0f) * fmaxf(ay1 - ay0, 0.0f);
    float ab = fmaxf(bx1 - bx0, 0.0f) * fmaxf(by1 - by0, 0.0f);
    float un = aa + ab - in_;
    float iou = (un > 0.0f) ? in_ / un : 0.0f;
    s_comb[f] = iou + SCORE_BONUS * s_scores[q];
  }
  __syncthreads();

  int lane = t & 63;
  if (t < 64) {
    // ---------------- wave 0: greedy NMS ----------------
    bool e1 = (lane < N_MASKS) && (s_scores[lane] >= SCORE_THR);
    bool e2 = (lane + 64 < N_MASKS) && (s_scores[lane + 64] >= SCORE_THR);
    bool any_elig = __any(e1 || e2);
    unsigned long long kept_lo = 0, kept_hi = 0;  // uniform across the wave
    for (int i = 0; i < N_MASKS; ++i) {
      int oi = s_order[i];
      bool c = false;
      if (lane < i && ((kept_lo >> lane) & 1ull))
        c = s_iou[oi * N_MASKS + s_order[lane]] > IOU_THR;
      int j2 = lane + 64;
      if (j2 < i && ((kept_hi >> lane) & 1ull))
        c |= s_iou[oi * N_MASKS + s_order[j2]] > IOU_THR;
      bool sup = __any(c);
      bool elig = any_elig ? (s_scores[oi] >= SCORE_THR) : true;
      if (elig && !sup) {
        if (i < 64) kept_lo |= 1ull << i;
        else kept_hi |= 1ull << (i - 64);
      }
    }
    for (int i = lane; i < N_MASKS; i += 64) {
      int oi = s_order[i];
      bool k = (i < 64) ? ((kept_lo >> i) & 1ull) : ((kept_hi >> (i - 64)) & 1ull);
      out[oi] = k ? s_scores[oi] : 0.0f;
    }
  } else {
    // ---------------- wave 1: greedy bipartite matching ----------------
    // Equivalent to scanning candidates in stable-sorted order: repeatedly
    // take the max-valued valid (p unassigned, q unused) pair, tie -> lowest
    // flat index f = p*96+q.
    unsigned assigned_p = 0;
    unsigned long long used_lo = 0, used_hi = 0;
    int assign_q[P_BOXES];
#pragma unroll
    for (int p = 0; p < P_BOXES; ++p) assign_q[p] = -1;

    for (int it = 0; it < P_BOXES; ++it) {
      float bv = -1.0f;
      int bf = 1 << 30;
#pragma unroll
      for (int k = 0; k < (P_BOXES * N_MASKS) / 64; ++k) {
        int f = lane + 64 * k;
        int p = f / N_MASKS, q = f % N_MASKS;
        bool pv = !((assigned_p >> p) & 1u);
        bool qv = (q < 64) ? !((used_lo >> q) & 1ull) : !((used_hi >> (q - 64)) & 1ull);
        if (pv && qv) {
          float v = s_comb[f];
          if (v > bv || (v == bv && f < bf)) { bv = v; bf = f; }
        }
      }
      for (int off = 32; off >= 1; off >>= 1) {
        float ov = __shfl_xor(bv, off);
        int of = __shfl_xor(bf, off);
        if (ov > bv || (ov == bv && of < bf)) { bv = ov; bf = of; }
      }
      if (bf < (1 << 30)) {
        int p = bf / N_MASKS, q = bf % N_MASKS;
        assigned_p |= 1u << p;
        if (q < 64) used_lo |= 1ull << q;
        else used_hi |= 1ull << (q - 64);
        assign_q[p] = q;
      }
    }
    // fallback: unmatched prompts take highest-score unused query (first max).
    // Unreachable for P=8 <= Q=96 but kept for semantic fidelity.
#pragma unroll
    for (int p = 0; p < P_BOXES; ++p) {
      if (assign_q[p] < 0) {
        float best = -1e30f;
        int bq = 0;
        for (int q = 0; q < N_MASKS; ++q) {
          bool used = (q < 64) ? ((used_lo >> q) & 1ull) : ((used_hi >> (q - 64)) & 1ull);
          float v = used ? -1e30f : s_scores[q];
          if (v > best) { best = v; bq = q; }
        }
        assign_q[p] = bq;
        if (bq < 64) used_lo |= 1ull << bq;
        else used_hi |= 1ull << (bq - 64);
      }
    }
#pragma unroll
    for (int p = 0; p < P_BOXES; ++p) {
      if (lane == p) out[N_MASKS + p] = s_comb[p * N_MASKS + assign_q[p]];
    }
  }
}

extern "C" void kernel_launch(void* const* d_in, const int* in_sizes, int n_in,
                              void* d_out, int out_size, void* d_ws, size_t ws_size,
                              hipStream_t stream) {
  const float* mask_logits = (const float*)d_in[0];
  const float* scores = (const float*)d_in[1];
  const float* pboxes = (const float*)d_in[2];
  const float* qboxes = (const float*)d_in[3];
  float* out = (float*)d_out;

  // workspace layout: [bits: TOTAL_WORDS u64][inter: 96*96 int]
  unsigned long long* bits = (unsigned long long*)d_ws;
  int* inter = (int*)((char*)d_ws + (size_t)TOTAL_WORDS * sizeof(unsigned long long));

  int n_groups = TOTAL_WORDS / 4;               // 98304 groups of 256 elements
  int pack_blocks = (n_groups * 64) / 256;      // exact: 24576
  pack_kernel<<<pack_blocks, 256, 0, stream>>>(
      (const float4*)mask_logits, bits, n_groups);

  dim3 g2(N_MASKS, N_MASKS);
  inter_kernel<<<g2, 256, 0, stream>>>(bits, inter);

  finalize_kernel<<<1, 128, 0, stream>>>(inter, scores, pboxes, qboxes, out);
}

// Round 2
// 65.916 us; speedup vs baseline: 1.2356x; 1.2356x over previous
//
#include <hip/hip_runtime.h>
#include <cstdint>
#include <cstddef>

#define N_MASKS 96
#define HW (512 * 512)
#define WORDS_PER_ROW (HW / 64)            // 4096 u64 words per mask row
#define TOTAL_WORDS (N_MASKS * WORDS_PER_ROW)
#define P_BOXES 8
#define IOU_THR 0.5f
#define SCORE_THR 0.5f
#define SCORE_BONUS 0.05f
#define TILE 4                              // 4x4 pairs per inter block

// ---------------------------------------------------------------------------
// Kernel 1: binarize mask logits into bit-packed rows.
// Each wave handles 4 consecutive 256-element groups: 4 float4 loads/lane in
// flight (MLP), 16 ballots, lane 0 stores 16 contiguous u64 (128 B).
// The bit permutation within each 256-element group is identical across rows,
// so AND+popcount results are unaffected.
// ---------------------------------------------------------------------------
__global__ __launch_bounds__(256) void pack_kernel(
    const float4* __restrict__ logits,
    unsigned long long* __restrict__ bits) {
  int wave = (blockIdx.x * blockDim.x + threadIdx.x) >> 6;  // global wave id
  int lane = threadIdx.x & 63;
  size_t g0 = (size_t)wave * 4;                             // first group
  float4 v0 = logits[(g0 + 0) * 64 + lane];
  float4 v1 = logits[(g0 + 1) * 64 + lane];
  float4 v2 = logits[(g0 + 2) * 64 + lane];
  float4 v3 = logits[(g0 + 3) * 64 + lane];
  unsigned long long m[16];
  m[0]  = __ballot(v0.x > 0.0f); m[1]  = __ballot(v0.y > 0.0f);
  m[2]  = __ballot(v0.z > 0.0f); m[3]  = __ballot(v0.w > 0.0f);
  m[4]  = __ballot(v1.x > 0.0f); m[5]  = __ballot(v1.y > 0.0f);
  m[6]  = __ballot(v1.z > 0.0f); m[7]  = __ballot(v1.w > 0.0f);
  m[8]  = __ballot(v2.x > 0.0f); m[9]  = __ballot(v2.y > 0.0f);
  m[10] = __ballot(v2.z > 0.0f); m[11] = __ballot(v2.w > 0.0f);
  m[12] = __ballot(v3.x > 0.0f); m[13] = __ballot(v3.y > 0.0f);
  m[14] = __ballot(v3.z > 0.0f); m[15] = __ballot(v3.w > 0.0f);
  if (lane == 0) {
    unsigned long long* dst = bits + g0 * 4;
#pragma unroll
    for (int k = 0; k < 16; ++k) dst[k] = m[k];
  }
}

// ---------------------------------------------------------------------------
// Kernel 2: pairwise intersection counts, 4x4 pairs per block.
// 256 threads stride over the 2048 ulonglong2 of each row; each thread holds
// 4 a-rows + 4 b-rows (16 B loads) and 16 accumulators.
// ---------------------------------------------------------------------------
__global__ __launch_bounds__(256) void inter_kernel(
    const unsigned long long* __restrict__ bits,
    int* __restrict__ inter) {
  int bi = blockIdx.y * TILE, bj = blockIdx.x * TILE;
  if (bj + TILE - 1 < bi) return;  // tile entirely strictly-lower: skip
  int t = threadIdx.x;
  const ulonglong2* base = (const ulonglong2*)bits;
  int acc[TILE * TILE];
#pragma unroll
  for (int k = 0; k < TILE * TILE; ++k) acc[k] = 0;

#pragma unroll
  for (int w = 0; w < (WORDS_PER_ROW / 2) / 256; ++w) {  // 8 iterations
    int idx = w * 256 + t;
    ulonglong2 a[TILE], b[TILE];
#pragma unroll
    for (int r = 0; r < TILE; ++r)
      a[r] = base[(size_t)(bi + r) * (WORDS_PER_ROW / 2) + idx];
#pragma unroll
    for (int c = 0; c < TILE; ++c)
      b[c] = base[(size_t)(bj + c) * (WORDS_PER_ROW / 2) + idx];
#pragma unroll
    for (int r = 0; r < TILE; ++r)
#pragma unroll
      for (int c = 0; c < TILE; ++c)
        acc[r * TILE + c] += __popcll(a[r].x & b[c].x) + __popcll(a[r].y & b[c].y);
  }
  // reduce 16 accumulators across the wave, then across 4 waves via LDS
#pragma unroll
  for (int k = 0; k < TILE * TILE; ++k)
    for (int off = 32; off >= 1; off >>= 1) acc[k] += __shfl_xor(acc[k], off);
  __shared__ int red[4][TILE * TILE];
  int wv = t >> 6;
  if ((t & 63) == 0) {
#pragma unroll
    for (int k = 0; k < TILE * TILE; ++k) red[wv][k] = acc[k];
  }
  __syncthreads();
  if (t < TILE * TILE) {
    int tot = red[0][t] + red[1][t] + red[2][t] + red[3][t];
    int i = bi + (t >> 2), j = bj + (t & 3);
    if (j >= i) {
      inter[i * N_MASKS + j] = tot;
      inter[j * N_MASKS + i] = tot;
    }
  }
}

// ---------------------------------------------------------------------------
// Kernel 3: NMS + greedy box matching. Single block, 128 threads (2 waves).
// Wave 0: stable-sorted greedy mask NMS. Wave 1: greedy bipartite matching.
// ---------------------------------------------------------------------------
__global__ __launch_bounds__(128) void finalize_kernel(
    const int* __restrict__ inter,
    const float* __restrict__ scores,
    const float* __restrict__ pboxes,
    const float* __restrict__ qboxes,
    float* __restrict__ out) {
  __shared__ float s_scores[N_MASKS];
  __shared__ float s_iou[N_MASKS * N_MASKS];
  __shared__ int s_order[N_MASKS];
  __shared__ float s_comb[P_BOXES * N_MASKS];
  __shared__ float s_pb[P_BOXES * 4];
  __shared__ float s_qb[N_MASKS * 4];
  int t = threadIdx.x;

  if (t < N_MASKS) s_scores[t] = scores[t];
  for (int k = t; k < P_BOXES * 4; k += 128) s_pb[k] = pboxes[k];
  for (int k = t; k < N_MASKS * 4; k += 128) s_qb[k] = qboxes[k];
  __syncthreads();

  // mask IoU matrix (exact: inter/area are small ints, exact in f32)
  for (int e = t; e < N_MASKS * N_MASKS; e += 128) {
    int i = e / N_MASKS, j = e % N_MASKS;
    float in_ = (float)inter[e];
    float un = (float)inter[i * N_MASKS + i] + (float)inter[j * N_MASKS + j] - in_;
    s_iou[e] = (un > 0.0f) ? in_ / un : 0.0f;
  }
  // stable descending rank of scores (tie -> smaller index first)
  if (t < N_MASKS) {
    float sc = s_scores[t];
    int r = 0;
    for (int m = 0; m < N_MASKS; ++m) {
      float sm = s_scores[m];
      if (sm > sc || (sm == sc && m < t)) ++r;
    }
    s_order[r] = t;
  }
  // combined = box_iou(prompt, query) + bonus * score
  for (int f = t; f < P_BOXES * N_MASKS; f += 128) {
    int p = f / N_MASKS, q = f % N_MASKS;
    float ax0 = s_pb[p * 4 + 0], ay0 = s_pb[p * 4 + 1];
    float ax1 = s_pb[p * 4 + 2], ay1 = s_pb[p * 4 + 3];
    float bx0 = s_qb[q * 4 + 0], by0 = s_qb[q * 4 + 1];
    float bx1 = s_qb[q * 4 + 2], by1 = s_qb[q * 4 + 3];
    float ltx = fmaxf(ax0, bx0), lty = fmaxf(ay0, by0);
    float rbx = fminf(ax1, bx1), rby = fminf(ay1, by1);
    float w = fmaxf(rbx - ltx, 0.0f), h = fmaxf(rby - lty, 0.0f);
    float in_ = w * h;
    float aa = fmaxf(ax1 - ax0, 0.0f) * fmaxf(ay1 - ay0, 0.0f);
    float ab = fmaxf(bx1 - bx0, 0.0f) * fmaxf(by1 - by0, 0.0f);
    float un = aa + ab - in_;
    float iou = (un > 0.0f) ? in_ / un : 0.0f;
    s_comb[f] = iou + SCORE_BONUS * s_scores[q];
  }
  __syncthreads();

  int lane = t & 63;
  if (t < 64) {
    // ---------------- wave 0: greedy NMS ----------------
    bool e1 = (lane < N_MASKS) && (s_scores[lane] >= SCORE_THR);
    bool e2 = (lane + 64 < N_MASKS) && (s_scores[lane + 64] >= SCORE_THR);
    bool any_elig = __any(e1 || e2);
    unsigned long long kept_lo = 0, kept_hi = 0;  // uniform across the wave
    for (int i = 0; i < N_MASKS; ++i) {
      int oi = s_order[i];
      bool c = false;
      if (lane < i && ((kept_lo >> lane) & 1ull))
        c = s_iou[oi * N_MASKS + s_order[lane]] > IOU_THR;
      int j2 = lane + 64;
      if (j2 < i && ((kept_hi >> lane) & 1ull))
        c |= s_iou[oi * N_MASKS + s_order[j2]] > IOU_THR;
      bool sup = __any(c);
      bool elig = any_elig ? (s_scores[oi] >= SCORE_THR) : true;
      if (elig && !sup) {
        if (i < 64) kept_lo |= 1ull << i;
        else kept_hi |= 1ull << (i - 64);
      }
    }
    for (int i = lane; i < N_MASKS; i += 64) {
      int oi = s_order[i];
      bool k = (i < 64) ? ((kept_lo >> i) & 1ull) : ((kept_hi >> (i - 64)) & 1ull);
      out[oi] = k ? s_scores[oi] : 0.0f;
    }
  } else {
    // ---------------- wave 1: greedy bipartite matching ----------------
    // Equivalent to scanning candidates in stable-sorted order: repeatedly
    // take the max-valued valid (p unassigned, q unused) pair, tie -> lowest
    // flat index f = p*96+q.
    unsigned assigned_p = 0;
    unsigned long long used_lo = 0, used_hi = 0;
    int assign_q[P_BOXES];
#pragma unroll
    for (int p = 0; p < P_BOXES; ++p) assign_q[p] = -1;

    for (int it = 0; it < P_BOXES; ++it) {
      float bv = -1.0f;
      int bf = 1 << 30;
#pragma unroll
      for (int k = 0; k < (P_BOXES * N_MASKS) / 64; ++k) {
        int f = lane + 64 * k;
        int p = f / N_MASKS, q = f % N_MASKS;
        bool pv = !((assigned_p >> p) & 1u);
        bool qv = (q < 64) ? !((used_lo >> q) & 1ull) : !((used_hi >> (q - 64)) & 1ull);
        if (pv && qv) {
          float v = s_comb[f];
          if (v > bv || (v == bv && f < bf)) { bv = v; bf = f; }
        }
      }
      for (int off = 32; off >= 1; off >>= 1) {
        float ov = __shfl_xor(bv, off);
        int of = __shfl_xor(bf, off);
        if (ov > bv || (ov == bv && of < bf)) { bv = ov; bf = of; }
      }
      if (bf < (1 << 30)) {
        int p = bf / N_MASKS, q = bf % N_MASKS;
        assigned_p |= 1u << p;
        if (q < 64) used_lo |= 1ull << q;
        else used_hi |= 1ull << (q - 64);
        assign_q[p] = q;
      }
    }
    // fallback: unmatched prompts take highest-score unused query (first max).
    // Unreachable for P=8 <= Q=96 but kept for semantic fidelity.
#pragma unroll
    for (int p = 0; p < P_BOXES; ++p) {
      if (assign_q[p] < 0) {
        float best = -1e30f;
        int bq = 0;
        for (int q = 0; q < N_MASKS; ++q) {
          bool used = (q < 64) ? ((used_lo >> q) & 1ull) : ((used_hi >> (q - 64)) & 1ull);
          float v = used ? -1e30f : s_scores[q];
          if (v > best) { best = v; bq = q; }
        }
        assign_q[p] = bq;
        if (bq < 64) used_lo |= 1ull << bq;
        else used_hi |= 1ull << (bq - 64);
      }
    }
#pragma unroll
    for (int p = 0; p < P_BOXES; ++p) {
      if (lane == p) out[N_MASKS + p] = s_comb[p * N_MASKS + assign_q[p]];
    }
  }
}

extern "C" void kernel_launch(void* const* d_in, const int* in_sizes, int n_in,
                              void* d_out, int out_size, void* d_ws, size_t ws_size,
                              hipStream_t stream) {
  const float* mask_logits = (const float*)d_in[0];
  const float* scores = (const float*)d_in[1];
  const float* pboxes = (const float*)d_in[2];
  const float* qboxes = (const float*)d_in[3];
  float* out = (float*)d_out;

  // workspace layout: [bits: TOTAL_WORDS u64][inter: 96*96 int]
  unsigned long long* bits = (unsigned long long*)d_ws;
  int* inter = (int*)((char*)d_ws + (size_t)TOTAL_WORDS * sizeof(unsigned long long));

  // pack: one wave per 4 groups of 256 elements -> 98304/4 = 24576 waves
  int total_waves = (TOTAL_WORDS / 4) / 4;      // 24576
  int pack_blocks = (total_waves * 64) / 256;   // 6144
  pack_kernel<<<pack_blocks, 256, 0, stream>>>((const float4*)mask_logits, bits);

  dim3 g2(N_MASKS / TILE, N_MASKS / TILE);      // 24 x 24
  inter_kernel<<<g2, 256, 0, stream>>>(bits, inter);

  finalize_kernel<<<1, 128, 0, stream>>>(inter, scores, pboxes, qboxes, out);
}